// Round 1
// baseline (1143.824 us; speedup 1.0000x reference)
//
#include <hip/hip_runtime.h>
#include <hip/hip_bf16.h>

#define NN 20000
#define NE 640000
#define F  128

typedef __attribute__((ext_vector_type(8))) short s16x8;
typedef __attribute__((ext_vector_type(4))) short s16x4;

__device__ __forceinline__ float bf16_to_f32(short x) {
    union { unsigned u; float f; } c;
    c.u = ((unsigned)(unsigned short)x) << 16;
    return c.f;
}

__global__ void k_zero(float* __restrict__ p, int n) {
    int i = blockIdx.x * blockDim.x + threadIdx.x;
    int st = gridDim.x * blockDim.x;
    for (; i < n; i += st) p[i] = 0.0f;
}

__global__ __launch_bounds__(256) void k_scatter(
        const float* __restrict__ ef, const int* __restrict__ dst,
        float* __restrict__ h, float* __restrict__ deg) {
    unsigned tid = blockIdx.x * 256u + threadIdx.x;
    unsigned e = tid >> 5;      // 32 float4 per 128-wide edge row
    unsigned f4 = tid & 31;
    if (e >= NE) return;
    int d = dst[e];
    const float4 v = *reinterpret_cast<const float4*>(ef + (size_t)e * F + f4 * 4);
    float* hp = h + (size_t)d * F + f4 * 4;
    atomicAdd(hp + 0, v.x);
    atomicAdd(hp + 1, v.y);
    atomicAdd(hp + 2, v.z);
    atomicAdd(hp + 3, v.w);
    if (f4 == 0) atomicAdd(deg + d, 1.0f);
}

// GEMM: out[n][o] = (sum_k h[n][k] * W[o][k] + b[o]) * rsqrt(max(deg[n],1))
// Tile: 64 nodes x 128 outs per 256-thread block.
// LDS: Wt[k][o] (bf16, ld=136) + hT[k][n] (bf16, ld=72) = 52 KB.
#define TM 64
#define WT_LD 136   // multiple of 8 -> 16B-aligned s16x4 loads for all k
#define HT_LD 72    // multiple of 8 -> 16B-aligned s16x8 loads

__global__ __launch_bounds__(256) void k_gemm(
        const float* __restrict__ h, const float* __restrict__ W,
        const float* __restrict__ bias, const float* __restrict__ deg,
        float* __restrict__ out) {
    __shared__ __hip_bfloat16 Wt[128 * WT_LD];
    __shared__ __hip_bfloat16 hT[128 * HT_LD];
    const int t = threadIdx.x;
    const int base = blockIdx.x * TM;

    // stage W^T: Wt[i][o] = W[o][i]; global read coalesced along i
    for (int e = t; e < F * F; e += 256) {
        int o = e >> 7, i = e & 127;
        Wt[i * WT_LD + o] = __float2bfloat16(W[e]);
    }
    // stage h^T: hT[k][n] = h[base+n][k]; global read coalesced along k
    for (int e = t; e < TM * F; e += 256) {
        int n = e >> 7, k = e & 127;
        int gn = base + n;
        hT[k * HT_LD + n] = __float2bfloat16(gn < NN ? h[(size_t)gn * F + k] : 0.0f);
    }
    __syncthreads();

    const int tx = t & 31, ty = t >> 5;
    const int o0 = tx * 4, n0 = ty * 8;

    float acc[8][4];
    #pragma unroll
    for (int i = 0; i < 8; ++i)
        #pragma unroll
        for (int j = 0; j < 4; ++j) acc[i][j] = 0.0f;

    #pragma unroll 4
    for (int k = 0; k < F; ++k) {
        s16x8 hv = *reinterpret_cast<const s16x8*>(&hT[k * HT_LD + n0]);
        s16x4 wv = *reinterpret_cast<const s16x4*>(&Wt[k * WT_LD + o0]);
        float wf[4], hf[8];
        #pragma unroll
        for (int j = 0; j < 4; ++j) wf[j] = bf16_to_f32(wv[j]);
        #pragma unroll
        for (int i = 0; i < 8; ++i) hf[i] = bf16_to_f32(hv[i]);
        #pragma unroll
        for (int i = 0; i < 8; ++i)
            #pragma unroll
            for (int j = 0; j < 4; ++j)
                acc[i][j] = fmaf(hf[i], wf[j], acc[i][j]);
    }

    const float4 bv = *reinterpret_cast<const float4*>(&bias[o0]);
    #pragma unroll
    for (int i = 0; i < 8; ++i) {
        int gn = base + n0 + i;
        if (gn >= NN) break;
        float s = rsqrtf(fmaxf(deg[gn], 1.0f));
        float4 r;
        r.x = (acc[i][0] + bv.x) * s;
        r.y = (acc[i][1] + bv.y) * s;
        r.z = (acc[i][2] + bv.z) * s;
        r.w = (acc[i][3] + bv.w) * s;
        *reinterpret_cast<float4*>(&out[(size_t)gn * F + o0]) = r;
    }
}

extern "C" void kernel_launch(void* const* d_in, const int* in_sizes, int n_in,
                              void* d_out, int out_size, void* d_ws, size_t ws_size,
                              hipStream_t stream) {
    // inputs: 0 node_feats (unused), 1 edge_feats, 2 W, 3 b, 4 src (unused), 5 dst
    const float* edge_feats = (const float*)d_in[1];
    const float* W          = (const float*)d_in[2];
    const float* bias       = (const float*)d_in[3];
    const int*   dst        = (const int*)d_in[5];
    float* out = (float*)d_out;

    float* h   = (float*)d_ws;                 // [NN*F]
    float* deg = h + (size_t)NN * F;           // [NN]

    k_zero<<<2048, 256, 0, stream>>>(h, NN * F + NN);
    k_scatter<<<(NE * 32) / 256, 256, 0, stream>>>(edge_feats, dst, h, deg);
    k_gemm<<<(NN + TM - 1) / TM, 256, 0, stream>>>(h, W, bias, deg, out);
}

// Round 2
// 220.374 us; speedup vs baseline: 5.1904x; 5.1904x over previous
//
#include <hip/hip_runtime.h>
#include <hip/hip_bf16.h>

#define NN 20000
#define NE 640000
#define F  128

typedef __attribute__((ext_vector_type(8))) short s16x8;
typedef __attribute__((ext_vector_type(4))) short s16x4;

__device__ __forceinline__ float bf16_to_f32(short x) {
    union { unsigned u; float f; } c;
    c.u = ((unsigned)(unsigned short)x) << 16;
    return c.f;
}

__global__ void k_zero_i(int* __restrict__ p, int n) {
    int i = blockIdx.x * blockDim.x + threadIdx.x;
    if (i < n) p[i] = 0;
}

__global__ __launch_bounds__(256) void k_hist(const int* __restrict__ dst,
                                              int* __restrict__ hist) {
    int e = blockIdx.x * 256 + threadIdx.x;
    if (e < NE) atomicAdd(&hist[dst[e]], 1);
}

// single-block exclusive scan of hist[0..NN) -> off[0..NN], cur copy
__global__ __launch_bounds__(1024) void k_scan(const int* __restrict__ hist,
                                               int* __restrict__ off,
                                               int* __restrict__ cur) {
    __shared__ int lsum[1024];
    const int t = threadIdx.x;
    const int CH = (NN + 1023) / 1024;  // 20
    const int b = t * CH;
    int s = 0;
    for (int i = 0; i < CH; ++i) {
        int idx = b + i;
        if (idx < NN) s += hist[idx];
    }
    lsum[t] = s;
    __syncthreads();
    for (int d = 1; d < 1024; d <<= 1) {
        int v = (t >= d) ? lsum[t - d] : 0;
        __syncthreads();
        lsum[t] += v;
        __syncthreads();
    }
    int run = (t == 0) ? 0 : lsum[t - 1];
    for (int i = 0; i < CH; ++i) {
        int idx = b + i;
        if (idx < NN) {
            off[idx] = run;
            cur[idx] = run;
            run += hist[idx];
        }
    }
    if (t == 1023) off[NN] = lsum[1023];
}

__global__ __launch_bounds__(256) void k_fill(const int* __restrict__ dst,
                                              int* __restrict__ cur,
                                              int* __restrict__ eid) {
    int e = blockIdx.x * 256 + threadIdx.x;
    if (e >= NE) return;
    int slot = atomicAdd(&cur[dst[e]], 1);
    eid[slot] = e;
}

// one wave per node: sum edge rows (512B coalesced reads), write bf16 h row
__global__ __launch_bounds__(256) void k_gather(const float* __restrict__ ef,
                                                const int* __restrict__ eid,
                                                const int* __restrict__ off,
                                                __hip_bfloat162* __restrict__ h) {
    int wid = (blockIdx.x * 256 + threadIdx.x) >> 6;  // node id
    int lane = threadIdx.x & 63;
    if (wid >= NN) return;
    int s = off[wid], e = off[wid + 1];
    float a0 = 0.0f, a1 = 0.0f;
    int i = s;
    for (; i + 1 < e; i += 2) {
        int e0 = eid[i], e1 = eid[i + 1];
        float2 v0 = *reinterpret_cast<const float2*>(ef + (size_t)e0 * F + lane * 2);
        float2 v1 = *reinterpret_cast<const float2*>(ef + (size_t)e1 * F + lane * 2);
        a0 += v0.x + v1.x;
        a1 += v0.y + v1.y;
    }
    if (i < e) {
        int e0 = eid[i];
        float2 v0 = *reinterpret_cast<const float2*>(ef + (size_t)e0 * F + lane * 2);
        a0 += v0.x;
        a1 += v0.y;
    }
    __hip_bfloat162 r;
    r.x = __float2bfloat16(a0);
    r.y = __float2bfloat16(a1);
    h[(size_t)wid * (F / 2) + lane] = r;
}

// GEMM: out[n][o] = (sum_k h[n][k]*W[o][k] + b[o]) * rsqrt(max(deg[n],1))
#define TM 64
#define WT_LD 136
#define HT_LD 72

__global__ __launch_bounds__(256) void k_gemm(
        const __hip_bfloat16* __restrict__ h, const float* __restrict__ W,
        const float* __restrict__ bias, const int* __restrict__ off,
        float* __restrict__ out) {
    __shared__ __hip_bfloat16 Wt[128 * WT_LD];
    __shared__ __hip_bfloat16 hT[128 * HT_LD];
    const int t = threadIdx.x;
    const int base = blockIdx.x * TM;

    for (int e = t; e < F * F; e += 256) {
        int o = e >> 7, i = e & 127;
        Wt[i * WT_LD + o] = __float2bfloat16(W[e]);
    }
    // stage h^T: 8B vector loads of 4 bf16 along k
    for (int e4 = t; e4 < TM * (F / 4); e4 += 256) {
        int n = e4 >> 5, k4 = e4 & 31;
        int gn = base + n;
        ushort4 v;
        if (gn < NN) v = *reinterpret_cast<const ushort4*>(h + (size_t)gn * F + k4 * 4);
        else v = ushort4{0, 0, 0, 0};
        int k = k4 * 4;
        hT[(k + 0) * HT_LD + n] = *reinterpret_cast<__hip_bfloat16*>(&v.x);
        hT[(k + 1) * HT_LD + n] = *reinterpret_cast<__hip_bfloat16*>(&v.y);
        hT[(k + 2) * HT_LD + n] = *reinterpret_cast<__hip_bfloat16*>(&v.z);
        hT[(k + 3) * HT_LD + n] = *reinterpret_cast<__hip_bfloat16*>(&v.w);
    }
    __syncthreads();

    const int tx = t & 31, ty = t >> 5;
    const int o0 = tx * 4, n0 = ty * 8;

    float acc[8][4];
    #pragma unroll
    for (int i = 0; i < 8; ++i)
        #pragma unroll
        for (int j = 0; j < 4; ++j) acc[i][j] = 0.0f;

    #pragma unroll 4
    for (int k = 0; k < F; ++k) {
        s16x8 hv = *reinterpret_cast<const s16x8*>(&hT[k * HT_LD + n0]);
        s16x4 wv = *reinterpret_cast<const s16x4*>(&Wt[k * WT_LD + o0]);
        float wf[4], hf[8];
        #pragma unroll
        for (int j = 0; j < 4; ++j) wf[j] = bf16_to_f32(wv[j]);
        #pragma unroll
        for (int i = 0; i < 8; ++i) hf[i] = bf16_to_f32(hv[i]);
        #pragma unroll
        for (int i = 0; i < 8; ++i)
            #pragma unroll
            for (int j = 0; j < 4; ++j)
                acc[i][j] = fmaf(hf[i], wf[j], acc[i][j]);
    }

    const float4 bv = *reinterpret_cast<const float4*>(&bias[o0]);
    #pragma unroll
    for (int i = 0; i < 8; ++i) {
        int gn = base + n0 + i;
        if (gn >= NN) break;
        float deg = (float)(off[gn + 1] - off[gn]);
        float s = rsqrtf(fmaxf(deg, 1.0f));
        float4 r;
        r.x = (acc[i][0] + bv.x) * s;
        r.y = (acc[i][1] + bv.y) * s;
        r.z = (acc[i][2] + bv.z) * s;
        r.w = (acc[i][3] + bv.w) * s;
        *reinterpret_cast<float4*>(&out[(size_t)gn * F + o0]) = r;
    }
}

extern "C" void kernel_launch(void* const* d_in, const int* in_sizes, int n_in,
                              void* d_out, int out_size, void* d_ws, size_t ws_size,
                              hipStream_t stream) {
    // inputs: 0 node_feats (unused), 1 edge_feats, 2 W, 3 b, 4 src (unused), 5 dst
    const float* edge_feats = (const float*)d_in[1];
    const float* W          = (const float*)d_in[2];
    const float* bias       = (const float*)d_in[3];
    const int*   dst        = (const int*)d_in[5];
    float* out = (float*)d_out;

    // workspace layout (bytes): eid[NE] | hist[NN] | off[NN+1] | cur[NN] | h_bf16[NN*F]
    int* eid  = (int*)d_ws;
    int* hist = eid + NE;
    int* off  = hist + NN;
    int* cur  = off + NN + 1;
    __hip_bfloat16* h = (__hip_bfloat16*)(cur + NN);

    k_zero_i<<<(NN + 255) / 256, 256, 0, stream>>>(hist, NN);
    k_hist<<<(NE + 255) / 256, 256, 0, stream>>>(dst, hist);
    k_scan<<<1, 1024, 0, stream>>>(hist, off, cur);
    k_fill<<<(NE + 255) / 256, 256, 0, stream>>>(dst, cur, eid);
    k_gather<<<(NN * 64 + 255) / 256, 256, 0, stream>>>(
        edge_feats, eid, off, (__hip_bfloat162*)h);
    k_gemm<<<(NN + TM - 1) / TM, 256, 0, stream>>>(h, W, bias, off, out);
}

// Round 3
// 198.851 us; speedup vs baseline: 5.7522x; 1.1082x over previous
//
#include <hip/hip_runtime.h>
#include <hip/hip_bf16.h>

#define NN 20000
#define NE 640000
#define F  128

typedef __attribute__((ext_vector_type(8))) short s16x8;
typedef __attribute__((ext_vector_type(4))) short s16x4;

__device__ __forceinline__ float bf16_to_f32(short x) {
    union { unsigned u; float f; } c;
    c.u = ((unsigned)(unsigned short)x) << 16;
    return c.f;
}

__global__ void k_zero_i(int* __restrict__ p, int n) {
    int i = blockIdx.x * blockDim.x + threadIdx.x;
    if (i < n) p[i] = 0;
}

// 4 edges per thread via int4
__global__ __launch_bounds__(256) void k_hist(const int* __restrict__ dst,
                                              int* __restrict__ hist) {
    int t = blockIdx.x * 256 + threadIdx.x;
    if (t * 4 >= NE) return;
    int4 d = reinterpret_cast<const int4*>(dst)[t];
    atomicAdd(&hist[d.x], 1);
    atomicAdd(&hist[d.y], 1);
    atomicAdd(&hist[d.z], 1);
    atomicAdd(&hist[d.w], 1);
}

// single-block exclusive scan of hist[0..NN) -> off[0..NN], cur copy
__global__ __launch_bounds__(1024) void k_scan(const int* __restrict__ hist,
                                               int* __restrict__ off,
                                               int* __restrict__ cur) {
    __shared__ int lsum[1024];
    const int t = threadIdx.x;
    const int CH = (NN + 1023) / 1024;  // 20
    const int b = t * CH;
    int loc[CH];
    int s = 0;
    for (int i = 0; i < CH; ++i) {
        int idx = b + i;
        loc[i] = (idx < NN) ? hist[idx] : 0;
        s += loc[i];
    }
    lsum[t] = s;
    __syncthreads();
    for (int d = 1; d < 1024; d <<= 1) {
        int v = (t >= d) ? lsum[t - d] : 0;
        __syncthreads();
        lsum[t] += v;
        __syncthreads();
    }
    int run = (t == 0) ? 0 : lsum[t - 1];
    for (int i = 0; i < CH; ++i) {
        int idx = b + i;
        if (idx < NN) {
            off[idx] = run;
            cur[idx] = run;
            run += loc[i];
        }
    }
    if (t == 1023) off[NN] = lsum[1023];
}

// 4 edges per thread via int4
__global__ __launch_bounds__(256) void k_fill(const int* __restrict__ dst,
                                              int* __restrict__ cur,
                                              int* __restrict__ eid) {
    int t = blockIdx.x * 256 + threadIdx.x;
    if (t * 4 >= NE) return;
    int4 d = reinterpret_cast<const int4*>(dst)[t];
    int e0 = t * 4;
    eid[atomicAdd(&cur[d.x], 1)] = e0;
    eid[atomicAdd(&cur[d.y], 1)] = e0 + 1;
    eid[atomicAdd(&cur[d.z], 1)] = e0 + 2;
    eid[atomicAdd(&cur[d.w], 1)] = e0 + 3;
}

// one wave per node, 4 edge rows in flight (2KB/wave outstanding)
__global__ __launch_bounds__(256) void k_gather(const float* __restrict__ ef,
                                                const int* __restrict__ eid,
                                                const int* __restrict__ off,
                                                __hip_bfloat162* __restrict__ h) {
    int wid = (blockIdx.x * 256 + threadIdx.x) >> 6;  // node id
    int lane = threadIdx.x & 63;
    if (wid >= NN) return;
    int s = off[wid], e = off[wid + 1];
    const float* base = ef + lane * 2;
    float a0 = 0.0f, a1 = 0.0f;
    int i = s;
    for (; i + 3 < e; i += 4) {
        int e0 = eid[i], e1 = eid[i + 1], e2 = eid[i + 2], e3 = eid[i + 3];
        float2 v0 = *reinterpret_cast<const float2*>(base + (size_t)e0 * F);
        float2 v1 = *reinterpret_cast<const float2*>(base + (size_t)e1 * F);
        float2 v2 = *reinterpret_cast<const float2*>(base + (size_t)e2 * F);
        float2 v3 = *reinterpret_cast<const float2*>(base + (size_t)e3 * F);
        a0 += (v0.x + v1.x) + (v2.x + v3.x);
        a1 += (v0.y + v1.y) + (v2.y + v3.y);
    }
    for (; i < e; ++i) {
        int e0 = eid[i];
        float2 v0 = *reinterpret_cast<const float2*>(base + (size_t)e0 * F);
        a0 += v0.x;
        a1 += v0.y;
    }
    __hip_bfloat162 r;
    r.x = __float2bfloat16(a0);
    r.y = __float2bfloat16(a1);
    h[(size_t)wid * (F / 2) + lane] = r;
}

// GEMM: out[n][o] = (sum_k h[n][k]*W[o][k] + b[o]) * rsqrt(max(deg[n],1))
#define TM 64
#define WT_LD 136
#define HT_LD 72

__global__ __launch_bounds__(256) void k_gemm(
        const __hip_bfloat16* __restrict__ h, const float* __restrict__ W,
        const float* __restrict__ bias, const int* __restrict__ off,
        float* __restrict__ out) {
    __shared__ __hip_bfloat16 Wt[128 * WT_LD];
    __shared__ __hip_bfloat16 hT[128 * HT_LD];
    const int t = threadIdx.x;
    const int base = blockIdx.x * TM;

    for (int e = t; e < F * F; e += 256) {
        int o = e >> 7, i = e & 127;
        Wt[i * WT_LD + o] = __float2bfloat16(W[e]);
    }
    for (int e4 = t; e4 < TM * (F / 4); e4 += 256) {
        int n = e4 >> 5, k4 = e4 & 31;
        int gn = base + n;
        ushort4 v;
        if (gn < NN) v = *reinterpret_cast<const ushort4*>(h + (size_t)gn * F + k4 * 4);
        else v = ushort4{0, 0, 0, 0};
        int k = k4 * 4;
        hT[(k + 0) * HT_LD + n] = *reinterpret_cast<__hip_bfloat16*>(&v.x);
        hT[(k + 1) * HT_LD + n] = *reinterpret_cast<__hip_bfloat16*>(&v.y);
        hT[(k + 2) * HT_LD + n] = *reinterpret_cast<__hip_bfloat16*>(&v.z);
        hT[(k + 3) * HT_LD + n] = *reinterpret_cast<__hip_bfloat16*>(&v.w);
    }
    __syncthreads();

    const int tx = t & 31, ty = t >> 5;
    const int o0 = tx * 4, n0 = ty * 8;

    float acc[8][4];
    #pragma unroll
    for (int i = 0; i < 8; ++i)
        #pragma unroll
        for (int j = 0; j < 4; ++j) acc[i][j] = 0.0f;

    #pragma unroll 4
    for (int k = 0; k < F; ++k) {
        s16x8 hv = *reinterpret_cast<const s16x8*>(&hT[k * HT_LD + n0]);
        s16x4 wv = *reinterpret_cast<const s16x4*>(&Wt[k * WT_LD + o0]);
        float wf[4], hf[8];
        #pragma unroll
        for (int j = 0; j < 4; ++j) wf[j] = bf16_to_f32(wv[j]);
        #pragma unroll
        for (int i = 0; i < 8; ++i) hf[i] = bf16_to_f32(hv[i]);
        #pragma unroll
        for (int i = 0; i < 8; ++i)
            #pragma unroll
            for (int j = 0; j < 4; ++j)
                acc[i][j] = fmaf(hf[i], wf[j], acc[i][j]);
    }

    const float4 bv = *reinterpret_cast<const float4*>(&bias[o0]);
    #pragma unroll
    for (int i = 0; i < 8; ++i) {
        int gn = base + n0 + i;
        if (gn >= NN) break;
        float deg = (float)(off[gn + 1] - off[gn]);
        float s = rsqrtf(fmaxf(deg, 1.0f));
        float4 r;
        r.x = (acc[i][0] + bv.x) * s;
        r.y = (acc[i][1] + bv.y) * s;
        r.z = (acc[i][2] + bv.z) * s;
        r.w = (acc[i][3] + bv.w) * s;
        *reinterpret_cast<float4*>(&out[(size_t)gn * F + o0]) = r;
    }
}

extern "C" void kernel_launch(void* const* d_in, const int* in_sizes, int n_in,
                              void* d_out, int out_size, void* d_ws, size_t ws_size,
                              hipStream_t stream) {
    // inputs: 0 node_feats (unused), 1 edge_feats, 2 W, 3 b, 4 src (unused), 5 dst
    const float* edge_feats = (const float*)d_in[1];
    const float* W          = (const float*)d_in[2];
    const float* bias       = (const float*)d_in[3];
    const int*   dst        = (const int*)d_in[5];
    float* out = (float*)d_out;

    // workspace layout: eid[NE] | hist[NN] | off[NN+1] | cur[NN] | h_bf16[NN*F]
    int* eid  = (int*)d_ws;
    int* hist = eid + NE;
    int* off  = hist + NN;
    int* cur  = off + NN + 1;
    __hip_bfloat16* h = (__hip_bfloat16*)(cur + NN);

    k_zero_i<<<(NN + 255) / 256, 256, 0, stream>>>(hist, NN);
    k_hist<<<(NE / 4 + 255) / 256, 256, 0, stream>>>(dst, hist);
    k_scan<<<1, 1024, 0, stream>>>(hist, off, cur);
    k_fill<<<(NE / 4 + 255) / 256, 256, 0, stream>>>(dst, cur, eid);
    k_gather<<<(NN * 64 + 255) / 256, 256, 0, stream>>>(
        edge_feats, eid, off, (__hip_bfloat162*)h);
    k_gemm<<<(NN + TM - 1) / TM, 256, 0, stream>>>(h, W, bias, off, out);
}